// Round 11
// baseline (190.475 us; speedup 1.0000x reference)
//
#include <hip/hip_runtime.h>

// CBC (classification-by-components) fused kernel, v10 = v9 + 2-row batching.
// x:[B,1024] f32, components:[5,1024] f32, reasonings:[5,3,2] f32 -> probs:[B,3] f32.
//
// Ladder: v1 35.4 / v4 39 / v5 47 / v6 44 / v7 128 / v8 49 / v9 35.2 (best).
// Falsified: occupancy (v4), duty-cycle phasing (v5/v6/v8), line-util (v8),
// DS-pipe (v9). Remaining: average outstanding bytes/CU (~30 KB) sits at the
// congested-latency knee (~18-20 KB min for 6.3 TB/s at ~1800cyc loaded
// latency). v10 doubles per-wave outstanding the only untried clean way:
// INTRA-iteration 2-row batching. Both adjacent rows' 8 dwordx4 (one 8 KB
// contiguous stretch) issue before any compute -- straight-line code, so the
// compiler emits a counted vmcnt(4) and row1's loads stay in flight through
// row0's compute+DPP reduction. No copies, no ping-pong, no cross-iteration
// carry. Epilogue: lanes 0-5 store both rows' 6 contiguous floats.

#define DD 1024
#define KK 5
#define CC 3
#define F4_PER_ROW (DD / 4)            // 256 float4 per row
#define F4_PER_LANE (F4_PER_ROW / 64)  // 4 per lane per row

// one DPP-shifted add step: v += dpp_move(v); invalid lanes contribute 0
template <int CTRL>
__device__ __forceinline__ float dpp_add(float v) {
    int moved = __builtin_amdgcn_update_dpp(
        0, __float_as_int(v), CTRL, 0xf, 0xf, true);
    return v + __int_as_float(moved);
}

// full 64-lane sum on the VALU pipe; result broadcast to all lanes via lane 63
__device__ __forceinline__ float wave_sum_dpp(float v) {
    v = dpp_add<0x111>(v);   // row_shr:1
    v = dpp_add<0x112>(v);   // row_shr:2
    v = dpp_add<0x114>(v);   // row_shr:4
    v = dpp_add<0x118>(v);   // row_shr:8
    v = dpp_add<0x142>(v);   // row_bcast:15
    v = dpp_add<0x143>(v);   // row_bcast:31 -> lane63 = full sum
    return __int_as_float(__builtin_amdgcn_readlane(__float_as_int(v), 63));
}

__global__ __launch_bounds__(256) void cbc_kernel(
    const float* __restrict__ x,
    const float* __restrict__ comps,
    const float* __restrict__ reas,
    float* __restrict__ out,
    int B)
{
    const int lane = threadIdx.x & 63;
    const int waves_per_block = blockDim.x >> 6;
    const int wave_global = blockIdx.x * waves_per_block + (threadIdx.x >> 6);
    const int n_waves = gridDim.x * waves_per_block;

    // --- component fragments into registers: lane i owns float4 columns j*64+i ---
    float4 cf[KK][F4_PER_LANE];
    const float4* comps4 = (const float4*)comps;
#pragma unroll
    for (int k = 0; k < KK; ++k)
#pragma unroll
        for (int j = 0; j < F4_PER_LANE; ++j)
            cf[k][j] = comps4[k * F4_PER_ROW + j * 64 + lane];

    // --- per-lane reasoning params for class c = lane mod 3 (lanes 0..5 used) ---
    // pk = A; nk = (1-A)*B; wv = pk-nk; bias = sum nk; invden = 1/sum(pk+nk)
    int c = lane;
    if (c >= CC) c -= CC;
    if (c >= CC) c = 0;    // lanes >= 6: dummy class 0
    float wv[KK], bias = 0.f, den = 0.f;
#pragma unroll
    for (int k = 0; k < KK; ++k) {
        float a = reas[k * (CC * 2) + c * 2 + 0];
        float b = reas[k * (CC * 2) + c * 2 + 1];
        a = fminf(fmaxf(a, 0.f), 1.f);
        b = fminf(fmaxf(b, 0.f), 1.f);
        float nk = (1.f - a) * b;
        wv[k] = a - nk;
        bias += nk;
        den  += a + nk;
    }
    const float invden = 1.f / den;

    const float4* x4 = (const float4*)x;
    const int npairs = B >> 1;          // two adjacent rows per iteration

    for (int p = wave_global; p < npairs; p += n_waves) {
        const size_t base = (size_t)p * 2 * F4_PER_ROW;

        // ---- issue BOTH rows' loads up front: 8 KB contiguous, 8 dwordx4;
        //      row0's compute only needs vmcnt(4) -> row1 stays in flight ----
        float4 xv0[F4_PER_LANE], xv1[F4_PER_LANE];
#pragma unroll
        for (int j = 0; j < F4_PER_LANE; ++j)
            xv0[j] = x4[base + j * 64 + lane];
#pragma unroll
        for (int j = 0; j < F4_PER_LANE; ++j)
            xv1[j] = x4[base + F4_PER_ROW + j * 64 + lane];

        float acc0[KK], acc1[KK];
#pragma unroll
        for (int k = 0; k < KK; ++k) { acc0[k] = 0.f; acc1[k] = 0.f; }

        // ---- row 0 compute (row 1 loads outstanding throughout) ----
#pragma unroll
        for (int j = 0; j < F4_PER_LANE; ++j) {
#pragma unroll
            for (int k = 0; k < KK; ++k) {
                float dx = xv0[j].x - cf[k][j].x;
                float dy = xv0[j].y - cf[k][j].y;
                float dz = xv0[j].z - cf[k][j].z;
                float dw = xv0[j].w - cf[k][j].w;
                acc0[k] += dx * dx;
                acc0[k] += dy * dy;
                acc0[k] += dz * dz;
                acc0[k] += dw * dw;
            }
        }

        // ---- row 0 reduction on VALU pipe (no memory ops: loads still fly) ----
        float d20[KK];
#pragma unroll
        for (int k = 0; k < KK; ++k) d20[k] = wave_sum_dpp(acc0[k]);

        // ---- row 1 compute ----
#pragma unroll
        for (int j = 0; j < F4_PER_LANE; ++j) {
#pragma unroll
            for (int k = 0; k < KK; ++k) {
                float dx = xv1[j].x - cf[k][j].x;
                float dy = xv1[j].y - cf[k][j].y;
                float dz = xv1[j].z - cf[k][j].z;
                float dw = xv1[j].w - cf[k][j].w;
                acc1[k] += dx * dx;
                acc1[k] += dy * dy;
                acc1[k] += dz * dz;
                acc1[k] += dw * dw;
            }
        }

        float d21[KK];
#pragma unroll
        for (int k = 0; k < KK; ++k) d21[k] = wave_sum_dpp(acc1[k]);

        // ---- epilogue: lanes 0..5 write 6 contiguous floats (both rows) ----
        if (lane < 2 * CC) {
            const bool second = lane >= CC;   // lanes 3..5 -> row 2p+1
            float num = bias;
#pragma unroll
            for (int k = 0; k < KK; ++k) {
                float d2 = second ? d21[k] : d20[k];   // cndmask, unrolled
                num += __expf(-0.5f * d2) * wv[k];     // variance = 1
            }
            out[(size_t)p * (2 * CC) + lane] = num * invden;
        }
    }
}

extern "C" void kernel_launch(void* const* d_in, const int* in_sizes, int n_in,
                              void* d_out, int out_size, void* d_ws, size_t ws_size,
                              hipStream_t stream) {
    const float* x = (const float*)d_in[0];
    const float* comps = (const float*)d_in[1];
    const float* reas = (const float*)d_in[2];
    float* out = (float*)d_out;
    const int B = in_sizes[0] / DD;   // 32768 rows

    // 1024 blocks x 256 threads = 4096 waves; 16384 row-pairs -> 4 pairs/wave.
    const int blocks = 1024;
    cbc_kernel<<<blocks, 256, 0, stream>>>(x, comps, reas, out, B);
}